// Round 3
// baseline (230.048 us; speedup 1.0000x reference)
//
#include <hip/hip_runtime.h>

typedef _Float16 half8 __attribute__((ext_vector_type(8)));
typedef _Float16 half4v __attribute__((ext_vector_type(4)));
typedef float f32x4 __attribute__((ext_vector_type(4)));

// ---------------------------------------------------------------- cvt f32->f16
struct CvtJobs {
    const float* src[7];
    _Float16* dst[7];
    int n[7];
};

__global__ __launch_bounds__(256) void cvt_kernel(CvtJobs j) {
    int job = blockIdx.y;
    const float* s = j.src[job];
    _Float16* d = j.dst[job];
    int n = j.n[job];
    for (int i = blockIdx.x * blockDim.x + threadIdx.x; i < n;
         i += gridDim.x * blockDim.x)
        d[i] = (_Float16)s[i];
}

// ---------------------------------------------------------------- generic GEMM
// C[M,N] = alpha * A[M,K] @ B[N,K]^T + bias   (A,B fp16 row-major, K contiguous)
// MODE 0: fp16 C (ldc);  MODE 1: fp32 C (ldc);  MODE 2: fp16 V-transpose scatter
// Batch: z -> (zb = z/ZH, zh = z%ZH), element offsets oXb/oXh.
template<int MODE>
__global__ __launch_bounds__(256) void gemm_tn(
    const _Float16* __restrict__ A, const _Float16* __restrict__ Bm,
    _Float16* __restrict__ Ch, float* __restrict__ Cf,
    const float* __restrict__ bias, float alpha,
    int M, int N, int K, int lda, int ldb, int ldc,
    long oAb, long oAh, long oBb, long oBh, long oCb, long oCh, int ZH)
{
    int z = blockIdx.z;
    int zb = z / ZH, zh = z - zb * ZH;
    A  += zb * oAb + zh * oAh;
    Bm += zb * oBb + zh * oBh;
    long coff = zb * oCb + zh * oCh;

    __shared__ _Float16 As[64][40];   // 32+8 pad: <=2-way (free) b128 reads
    __shared__ _Float16 Bs[64][40];

    int tid = threadIdx.x;
    int l = tid & 63, w = tid >> 6;
    int wm = (w >> 1) * 32, wn = (w & 1) * 32;
    int m0 = blockIdx.x * 64, n0 = blockIdx.y * 64;
    int lr = tid >> 2, lc = (tid & 3) * 8;   // staging coords
    int ko = (l >> 4) * 8;                   // frag K offset

    f32x4 acc[2][2]{};

    for (int k0 = 0; k0 < K; k0 += 32) {
        half8 av = *(const half8*)(A + (long)(m0 + lr) * lda + k0 + lc);
        half8 bv{};
        if (n0 + lr < N)
            bv = *(const half8*)(Bm + (long)(n0 + lr) * ldb + k0 + lc);
        __syncthreads();
        *(half8*)(&As[lr][lc]) = av;
        *(half8*)(&Bs[lr][lc]) = bv;
        __syncthreads();
        half8 a0 = *(const half8*)(&As[wm + (l & 15)][ko]);
        half8 a1 = *(const half8*)(&As[wm + 16 + (l & 15)][ko]);
        half8 b0 = *(const half8*)(&Bs[wn + (l & 15)][ko]);
        half8 b1 = *(const half8*)(&Bs[wn + 16 + (l & 15)][ko]);
        acc[0][0] = __builtin_amdgcn_mfma_f32_16x16x32_f16(a0, b0, acc[0][0], 0, 0, 0);
        acc[0][1] = __builtin_amdgcn_mfma_f32_16x16x32_f16(a0, b1, acc[0][1], 0, 0, 0);
        acc[1][0] = __builtin_amdgcn_mfma_f32_16x16x32_f16(a1, b0, acc[1][0], 0, 0, 0);
        acc[1][1] = __builtin_amdgcn_mfma_f32_16x16x32_f16(a1, b1, acc[1][1], 0, 0, 0);
    }

    // C/D layout (16x16x32): col = lane&15, row = (lane>>4)*4 + i   [m89-verified]
    #pragma unroll
    for (int mm = 0; mm < 2; ++mm)
    #pragma unroll
    for (int nn = 0; nn < 2; ++nn) {
        int row  = wm + mm * 16 + (l >> 4) * 4;
        int colg = n0 + wn + nn * 16 + (l & 15);
        float bc = bias ? bias[colg < N ? colg : 0] : 0.f;
        if (MODE == 2) {
            // V-projection with transposed store: vt[(b*8+h)*32 + d][t]
            half4v hv;
            #pragma unroll
            for (int i = 0; i < 4; ++i)
                hv[i] = (_Float16)(acc[mm][nn][i] * alpha + bc);
            int grow = m0 + row;             // = b*512 + t  (4 consecutive t)
            int bb = grow >> 9, t = grow & 511;
            long off = ((long)(bb * 8 + (colg >> 5)) * 32 + (colg & 31)) * 512 + t;
            *(half4v*)(Ch + off) = hv;
        } else if (MODE == 0) {
            if (colg < N) {
                #pragma unroll
                for (int i = 0; i < 4; ++i)
                    Ch[coff + (long)(m0 + row + i) * ldc + colg] =
                        (_Float16)(acc[mm][nn][i] * alpha + bc);
            }
        } else {
            if (colg < N) {
                #pragma unroll
                for (int i = 0; i < 4; ++i)
                    Cf[coff + (long)(m0 + row + i) * ldc + colg] =
                        acc[mm][nn][i] * alpha + bc;
            }
        }
    }
}

// ---------------------------------------------------------------- row softmax
__global__ __launch_bounds__(512) void softmax_kernel(
    const _Float16* __restrict__ S, _Float16* __restrict__ P)
{
    long base = (long)blockIdx.x * 512;
    int tid = threadIdx.x;
    float v = (float)S[base + tid];
    float m = v;
    #pragma unroll
    for (int off = 32; off; off >>= 1) m = fmaxf(m, __shfl_xor(m, off, 64));
    __shared__ float rm[8], rsum[8];
    int w = tid >> 6;
    if ((tid & 63) == 0) rm[w] = m;
    __syncthreads();
    float mx = rm[0];
    #pragma unroll
    for (int i = 1; i < 8; ++i) mx = fmaxf(mx, rm[i]);
    float e = __expf(v - mx);
    float s = e;
    #pragma unroll
    for (int off = 32; off; off >>= 1) s += __shfl_xor(s, off, 64);
    if ((tid & 63) == 0) rsum[w] = s;
    __syncthreads();
    float tot = rsum[0];
    #pragma unroll
    for (int i = 1; i < 8; ++i) tot += rsum[i];
    P[base + tid] = (_Float16)(e / tot);
}

// ---------------------------------------------------------------- residual + LN
__global__ __launch_bounds__(256) void ln_kernel(
    const float* __restrict__ det, const float* __restrict__ att,
    const float* __restrict__ g, const float* __restrict__ bta,
    _Float16* __restrict__ xn)
{
    int row = blockIdx.x, tid = threadIdx.x;
    long idx = (long)row * 256 + tid;
    float x = det[idx] + att[idx];
    float s1 = x, s2 = x * x;
    #pragma unroll
    for (int off = 32; off; off >>= 1) {
        s1 += __shfl_xor(s1, off, 64);
        s2 += __shfl_xor(s2, off, 64);
    }
    __shared__ float r1[4], r2[4];
    if ((tid & 63) == 0) { r1[tid >> 6] = s1; r2[tid >> 6] = s2; }
    __syncthreads();
    float S1 = r1[0] + r1[1] + r1[2] + r1[3];
    float S2 = r2[0] + r2[1] + r2[2] + r2[3];
    float mean = S1 * (1.f / 256.f);
    float var  = S2 * (1.f / 256.f) - mean * mean;
    float rs = rsqrtf(var + 1e-5f);
    xn[idx] = (_Float16)((x - mean) * rs * g[tid] + bta[tid]);
}

// ---------------------------------------------------------------- pairwise MLP
// Rotate-based 16-lane reduction: after ror {8,4,2,1} EVERY lane holds the
// full 16-lane sum (direction-agnostic, unlike row_shr/row_shl).
template<int N_DPP>
__device__ __forceinline__ float dpp_row_ror(float x) {
    return __int_as_float(__builtin_amdgcn_update_dpp(
        0, __float_as_int(x), 0x120 | N_DPP, 0xF, 0xF, true));
}

// grid (8 n-tiles, 16 t-tiles, 4 b), 256 threads (4 waves).
// Per block: 64 n-rows x 32 t-cols. Wave w owns h' cols [32w, 32w+32).
// W1 frags (16x half8 = 64 VGPR) and xn frags (32x half8 = 128 VGPR) in registers.
__global__ __launch_bounds__(256, 2) void mlp_kernel(
    const _Float16* __restrict__ xn, const _Float16* __restrict__ trk,
    const _Float16* __restrict__ w1, const float* __restrict__ w2,
    const float* __restrict__ b1, const float* __restrict__ b2,
    float* __restrict__ out)
{
    int b  = blockIdx.z;
    int n0 = blockIdx.x * 64;
    int t0 = blockIdx.y * 32;
    int tid = threadIdx.x;
    int l = tid & 63, w = tid >> 6;
    int l15 = l & 15, g = l >> 4;
    int ko = g * 8;

    __shared__ _Float16 ts[32][264];    // tracks tile, padded
    __shared__ float part[4][32][65];   // per-wave fp32 partial logits [w][t][n]

    // stage tracks tile 32x256
    {
        const _Float16* src = trk + ((long)b * 512 + t0) * 256;
        int r = tid >> 3, c0 = (tid & 7) * 8;
        #pragma unroll
        for (int c = 0; c < 256; c += 64)
            *(half8*)(&ts[r][c + c0]) = *(const half8*)(src + r * 256 + c + c0);
    }

    // register-resident W1 fragments (B operand: row = h', K contiguous)
    int c0 = w * 32 + l15;
    half8 bf[2][8];
    {
        const _Float16* w1p = w1 + c0 * 256 + ko;
        #pragma unroll
        for (int ns = 0; ns < 2; ++ns)
            #pragma unroll
            for (int ks = 0; ks < 8; ++ks)
                bf[ns][ks] = *(const half8*)(w1p + ns * 16 * 256 + ks * 32);
    }
    float w2v0 = w2[c0], w2v1 = w2[c0 + 16];
    float b1v0 = b1[c0], b1v1 = b1[c0 + 16];

    // register-resident xn fragments (A operand: row = n, K contiguous)
    half8 xnf[4][8];
    {
        const _Float16* xb = xn + ((long)b * 512 + n0) * 256 + l15 * 256 + ko;
        #pragma unroll
        for (int m = 0; m < 4; ++m)
            #pragma unroll
            for (int ks = 0; ks < 8; ++ks)
                xnf[m][ks] = *(const half8*)(xb + m * 16 * 256 + ks * 32);
    }

    __syncthreads();

    for (int tl = 0; tl < 32; ++tl) {
        f32x4 acc[4][2]{};
        #pragma unroll
        for (int ks = 0; ks < 8; ++ks) {
            half8 tf = *(const half8*)(&ts[tl][ks * 32 + ko]);
            #pragma unroll
            for (int m = 0; m < 4; ++m) {
                half8 p = xnf[m][ks] * tf;   // v_pk_mul_f16 x4
                acc[m][0] = __builtin_amdgcn_mfma_f32_16x16x32_f16(p, bf[0][ks], acc[m][0], 0, 0, 0);
                acc[m][1] = __builtin_amdgcn_mfma_f32_16x16x32_f16(p, bf[1][ks], acc[m][1], 0, 0, 0);
            }
        }
        // epilogue: relu + w2 dot; reduce over the 16 col-lanes via DPP row_ror
        #pragma unroll
        for (int m = 0; m < 4; ++m) {
            float v[4];
            #pragma unroll
            for (int i = 0; i < 4; ++i) {
                float h0 = fmaxf(acc[m][0][i] + b1v0, 0.f);
                float h1 = fmaxf(acc[m][1][i] + b1v1, 0.f);
                float x = fmaf(h0, w2v0, h1 * w2v1);
                x += dpp_row_ror<8>(x);
                x += dpp_row_ror<4>(x);
                x += dpp_row_ror<2>(x);
                x += dpp_row_ror<1>(x);
                v[i] = x;    // full 16-lane sum in every lane
            }
            if (l15 == 0) {
                #pragma unroll
                for (int i = 0; i < 4; ++i)
                    part[w][tl][m * 16 + g * 4 + i] = v[i];
            }
        }
    }
    __syncthreads();

    // combine 4 wave partials + bias, sigmoid, store
    float b2v = b2[0];
    int t = tid & 31;
    int nbase = tid >> 5;
    float* op = out + ((long)b * 512 + n0) * 512 + t0;
    #pragma unroll
    for (int k = 0; k < 8; ++k) {
        int nn = nbase + k * 8;
        float s = part[0][t][nn] + part[1][t][nn]
                + part[2][t][nn] + part[3][t][nn] + b2v;
        op[(long)nn * 512 + t] = 1.f / (1.f + __expf(-s));
    }
}

// ---------------------------------------------------------------- launch
extern "C" void kernel_launch(void* const* d_in, const int* in_sizes, int n_in,
                              void* d_out, int out_size, void* d_ws, size_t ws_size,
                              hipStream_t stream)
{
    const float* det  = (const float*)d_in[0];
    const float* trk  = (const float*)d_in[1];
    const float* w_q  = (const float*)d_in[2];
    const float* b_q  = (const float*)d_in[3];
    const float* w_k  = (const float*)d_in[4];
    const float* b_k  = (const float*)d_in[5];
    const float* w_v  = (const float*)d_in[6];
    const float* b_v  = (const float*)d_in[7];
    const float* w_o  = (const float*)d_in[8];
    const float* b_o  = (const float*)d_in[9];
    const float* ln_g = (const float*)d_in[10];
    const float* ln_b = (const float*)d_in[11];
    const float* w1   = (const float*)d_in[12];
    const float* b1   = (const float*)d_in[13];
    const float* w2   = (const float*)d_in[14];
    const float* b2   = (const float*)d_in[15];
    float* out = (float*)d_out;

    char* ws = (char*)d_ws;
    const size_t O_DETH = 0;                       // 2048x256 f16   1 MB
    const size_t O_TRKH = O_DETH + (size_t)1048576;
    const size_t O_WQH  = O_TRKH + (size_t)1048576;
    const size_t O_WKH  = O_WQH + 131072;
    const size_t O_WVH  = O_WKH + 131072;
    const size_t O_WOH  = O_WVH + 131072;
    const size_t O_W1H  = O_WOH + 131072;
    const size_t O_QH   = O_W1H + 65536;
    const size_t O_KH   = O_QH + (size_t)1048576;
    const size_t O_VT   = O_KH + (size_t)1048576;  // [bh][d][t] f16 1 MB
    const size_t O_CTXH = O_VT + (size_t)1048576;
    const size_t O_XNH  = O_CTXH + (size_t)1048576;
    const size_t O_ATT  = O_XNH + (size_t)1048576; // fp32 attended 2 MB
    const size_t O_SC   = O_ATT + (size_t)2097152; // scores f16 16 MB
    const size_t O_ATTN = O_SC + (size_t)16777216; // attn f16 16 MB

    _Float16* det_h  = (_Float16*)(ws + O_DETH);
    _Float16* trk_h  = (_Float16*)(ws + O_TRKH);
    _Float16* wq_h   = (_Float16*)(ws + O_WQH);
    _Float16* wk_h   = (_Float16*)(ws + O_WKH);
    _Float16* wv_h   = (_Float16*)(ws + O_WVH);
    _Float16* wo_h   = (_Float16*)(ws + O_WOH);
    _Float16* w1_h   = (_Float16*)(ws + O_W1H);
    _Float16* Q_h    = (_Float16*)(ws + O_QH);
    _Float16* K_h    = (_Float16*)(ws + O_KH);
    _Float16* vt     = (_Float16*)(ws + O_VT);
    _Float16* ctx_h  = (_Float16*)(ws + O_CTXH);
    _Float16* xn_h   = (_Float16*)(ws + O_XNH);
    float*    att_f  = (float*)(ws + O_ATT);
    _Float16* sc_h   = (_Float16*)(ws + O_SC);
    _Float16* attn_h = (_Float16*)(ws + O_ATTN);

    CvtJobs cj;
    cj.src[0] = det; cj.dst[0] = det_h; cj.n[0] = 2048 * 256;
    cj.src[1] = trk; cj.dst[1] = trk_h; cj.n[1] = 2048 * 256;
    cj.src[2] = w_q; cj.dst[2] = wq_h;  cj.n[2] = 65536;
    cj.src[3] = w_k; cj.dst[3] = wk_h;  cj.n[3] = 65536;
    cj.src[4] = w_v; cj.dst[4] = wv_h;  cj.n[4] = 65536;
    cj.src[5] = w_o; cj.dst[5] = wo_h;  cj.n[5] = 65536;
    cj.src[6] = w1;  cj.dst[6] = w1_h;  cj.n[6] = 32768;
    cvt_kernel<<<dim3(512, 7), 256, 0, stream>>>(cj);

    // Q = det @ wq^T + bq   (2048x256x256)
    gemm_tn<0><<<dim3(32, 4, 1), 256, 0, stream>>>(det_h, wq_h, Q_h, nullptr, b_q, 1.f,
        2048, 256, 256, 256, 256, 256, 0, 0, 0, 0, 0, 0, 1);
    // K = trk @ wk^T + bk
    gemm_tn<0><<<dim3(32, 4, 1), 256, 0, stream>>>(trk_h, wk_h, K_h, nullptr, b_k, 1.f,
        2048, 256, 256, 256, 256, 256, 0, 0, 0, 0, 0, 0, 1);
    // V = trk @ wv^T + bv, stored transposed as vt[bh][d][t]
    gemm_tn<2><<<dim3(32, 4, 1), 256, 0, stream>>>(trk_h, wv_h, vt, nullptr, b_v, 1.f,
        2048, 256, 256, 256, 256, 256, 0, 0, 0, 0, 0, 0, 1);
    // scores[bh][q][k] = (Q . K) / sqrt(32);  z = b*8+h
    gemm_tn<0><<<dim3(8, 8, 32), 256, 0, stream>>>(Q_h, K_h, sc_h, nullptr, nullptr,
        0.17677669529663687f,
        512, 512, 32, 256, 256, 512,
        131072, 32, 131072, 32, 2097152, 262144, 8);
    // softmax over k
    softmax_kernel<<<16384, 512, 0, stream>>>(sc_h, attn_h);
    // ctx[b][q][h*32+d] = attn @ V
    gemm_tn<0><<<dim3(8, 1, 32), 256, 0, stream>>>(attn_h, vt, ctx_h, nullptr, nullptr, 1.f,
        512, 32, 512, 512, 512, 256,
        2097152, 262144, 131072, 16384, 131072, 32, 8);
    // attended = ctx @ wo^T + bo  (fp32)
    gemm_tn<1><<<dim3(32, 4, 1), 256, 0, stream>>>(ctx_h, wo_h, nullptr, att_f, b_o, 1.f,
        2048, 256, 256, 256, 256, 256, 0, 0, 0, 0, 0, 0, 1);
    // xn = LN(det + attended)  -> fp16
    ln_kernel<<<2048, 256, 0, stream>>>(det, att_f, ln_g, ln_b, xn_h);
    // association MLP + sigmoid
    mlp_kernel<<<dim3(8, 16, 4), 256, 0, stream>>>(xn_h, trk_h, w1_h, w2, b1, b2, out);

    (void)in_sizes; (void)n_in; (void)out_size; (void)ws_size; (void)O_ATTN;
}

// Round 4
// 195.389 us; speedup vs baseline: 1.1774x; 1.1774x over previous
//
#include <hip/hip_runtime.h>

typedef _Float16 half8 __attribute__((ext_vector_type(8)));
typedef _Float16 half4v __attribute__((ext_vector_type(4)));
typedef _Float16 half2v __attribute__((ext_vector_type(2)));
typedef float f32x4 __attribute__((ext_vector_type(4)));

// ---------------------------------------------------------------- cvt f32->f16
struct CvtJobs {
    const float* src[7];
    _Float16* dst[7];
    int n[7];
};

__global__ __launch_bounds__(256) void cvt_kernel(CvtJobs j) {
    int job = blockIdx.y;
    const float* s = j.src[job];
    _Float16* d = j.dst[job];
    int n = j.n[job];
    for (int i = blockIdx.x * blockDim.x + threadIdx.x; i < n;
         i += gridDim.x * blockDim.x)
        d[i] = (_Float16)s[i];
}

// ---------------------------------------------------------------- generic GEMM
// C[M,N] = alpha * A[M,K] @ B[N,K]^T + bias   (A,B fp16 row-major, K contiguous)
// MODE 0: fp16 C (ldc);  MODE 1: fp32 C (ldc);  MODE 2: fp16 V-transpose scatter
template<int MODE>
__global__ __launch_bounds__(256) void gemm_tn(
    const _Float16* __restrict__ A, const _Float16* __restrict__ Bm,
    _Float16* __restrict__ Ch, float* __restrict__ Cf,
    const float* __restrict__ bias, float alpha,
    int M, int N, int K, int lda, int ldb, int ldc)
{
    __shared__ _Float16 As[64][40];   // +8 pad: <=2-way (free) b128 reads
    __shared__ _Float16 Bs[64][40];

    int tid = threadIdx.x;
    int l = tid & 63, w = tid >> 6;
    int wm = (w >> 1) * 32, wn = (w & 1) * 32;
    int m0 = blockIdx.x * 64, n0 = blockIdx.y * 64;
    int lr = tid >> 2, lc = (tid & 3) * 8;   // staging coords
    int ko = (l >> 4) * 8;                   // frag K offset

    f32x4 acc[2][2]{};

    for (int k0 = 0; k0 < K; k0 += 32) {
        half8 av = *(const half8*)(A + (long)(m0 + lr) * lda + k0 + lc);
        half8 bv = *(const half8*)(Bm + (long)(n0 + lr) * ldb + k0 + lc);
        __syncthreads();
        *(half8*)(&As[lr][lc]) = av;
        *(half8*)(&Bs[lr][lc]) = bv;
        __syncthreads();
        half8 a0 = *(const half8*)(&As[wm + (l & 15)][ko]);
        half8 a1 = *(const half8*)(&As[wm + 16 + (l & 15)][ko]);
        half8 b0 = *(const half8*)(&Bs[wn + (l & 15)][ko]);
        half8 b1 = *(const half8*)(&Bs[wn + 16 + (l & 15)][ko]);
        acc[0][0] = __builtin_amdgcn_mfma_f32_16x16x32_f16(a0, b0, acc[0][0], 0, 0, 0);
        acc[0][1] = __builtin_amdgcn_mfma_f32_16x16x32_f16(a0, b1, acc[0][1], 0, 0, 0);
        acc[1][0] = __builtin_amdgcn_mfma_f32_16x16x32_f16(a1, b0, acc[1][0], 0, 0, 0);
        acc[1][1] = __builtin_amdgcn_mfma_f32_16x16x32_f16(a1, b1, acc[1][1], 0, 0, 0);
    }

    // C/D layout (16x16x32): col = lane&15 (B-row), row = (lane>>4)*4 + i (A-row)
    #pragma unroll
    for (int mm = 0; mm < 2; ++mm)
    #pragma unroll
    for (int nn = 0; nn < 2; ++nn) {
        int row  = wm + mm * 16 + (l >> 4) * 4;
        int colg = n0 + wn + nn * 16 + (l & 15);
        float bc = bias ? bias[colg] : 0.f;
        if (MODE == 2) {
            // V-projection with transposed store: vt[(b*8+h)*32 + d][t]
            half4v hv;
            #pragma unroll
            for (int i = 0; i < 4; ++i)
                hv[i] = (_Float16)(acc[mm][nn][i] * alpha + bc);
            int grow = m0 + row;             // = b*512 + t  (4 consecutive t)
            int bb = grow >> 9, t = grow & 511;
            long off = ((long)(bb * 8 + (colg >> 5)) * 32 + (colg & 31)) * 512 + t;
            *(half4v*)(Ch + off) = hv;
        } else if (MODE == 0) {
            #pragma unroll
            for (int i = 0; i < 4; ++i)
                Ch[(long)(m0 + row + i) * ldc + colg] =
                    (_Float16)(acc[mm][nn][i] * alpha + bc);
        } else {
            #pragma unroll
            for (int i = 0; i < 4; ++i)
                Cf[(long)(m0 + row + i) * ldc + colg] =
                    acc[mm][nn][i] * alpha + bc;
        }
    }
}

// ---------------------------------------------------------------- fused attention
// One block = 64 q-rows x one (b,h). 4 waves x 16 q.
// S^T = MFMA(K, Q): rows(k) on reg axis, cols(q) = lane&15 -> per-lane softmax
// (only xor16/xor32 cross-group), then PV = MFMA(V^T, P) via per-wave LDS P.
__global__ __launch_bounds__(256) void flash_kernel(
    const _Float16* __restrict__ Q, const _Float16* __restrict__ K,
    const _Float16* __restrict__ vt, _Float16* __restrict__ ctx)
{
    __shared__ _Float16 P[4][16][264];   // per-wave half-P: [q16][k256 + 8 pad]
    int bh = blockIdx.y, b = bh >> 3, h = bh & 7;
    int q0 = blockIdx.x * 64;
    int tid = threadIdx.x, l = tid & 63, w = tid >> 6;
    int l15 = l & 15, g = l >> 4;

    // Q frag (B operand): row=l15 -> q, elems d = g*8..+7, pre-scaled by 1/sqrt(32)
    const _Float16* qp = Q + ((long)b * 512 + q0 + w * 16 + l15) * 256 + h * 32 + g * 8;
    half8 qf = *(const half8*)qp;
    #pragma unroll
    for (int i = 0; i < 8; ++i) qf[i] = qf[i] * (_Float16)0.17677669529663687f;

    // S^T tiles: 32 k-tiles of 16; A = K rows (k), lane row l15 -> k = 16t + l15
    const _Float16* kp = K + ((long)b * 512 + l15) * 256 + h * 32 + g * 8;
    f32x4 s[32];
    f32x4 zero{};
    #pragma unroll
    for (int t = 0; t < 32; ++t) {
        half8 kf = *(const half8*)(kp + (long)t * (16 * 256));
        s[t] = __builtin_amdgcn_mfma_f32_16x16x32_f16(kf, qf, zero, 0, 0, 0);
    }
    // per lane: k = 16t + g*4 + i for its q = l15. softmax over k.
    float m0 = -3e38f, m1 = -3e38f, m2 = -3e38f, m3 = -3e38f;
    #pragma unroll
    for (int t = 0; t < 32; ++t) {
        m0 = fmaxf(m0, s[t][0]); m1 = fmaxf(m1, s[t][1]);
        m2 = fmaxf(m2, s[t][2]); m3 = fmaxf(m3, s[t][3]);
    }
    float m = fmaxf(fmaxf(m0, m1), fmaxf(m2, m3));
    m = fmaxf(m, __shfl_xor(m, 16, 64));
    m = fmaxf(m, __shfl_xor(m, 32, 64));
    float s0 = 0.f, s1 = 0.f, s2 = 0.f, s3 = 0.f;
    #pragma unroll
    for (int t = 0; t < 32; ++t) {
        s[t][0] = __expf(s[t][0] - m); s0 += s[t][0];
        s[t][1] = __expf(s[t][1] - m); s1 += s[t][1];
        s[t][2] = __expf(s[t][2] - m); s2 += s[t][2];
        s[t][3] = __expf(s[t][3] - m); s3 += s[t][3];
    }
    float sum = (s0 + s1) + (s2 + s3);
    sum += __shfl_xor(sum, 16, 64);
    sum += __shfl_xor(sum, 32, 64);
    float rs = 1.f / sum;   // folded into ctx epilogue; P stored unnormalized

    // PV: ctx^T[d,q] = sum_k V^T[d,k] P[q,k], in 2 k-phases of 256
    f32x4 c0{}, c1{};
    const _Float16* vp = vt + ((long)bh * 32 + l15) * 512 + g * 8;
    #pragma unroll
    for (int hf = 0; hf < 2; ++hf) {
        #pragma unroll
        for (int t = 0; t < 16; ++t) {
            int tt = hf * 16 + t;
            half2v p01, p23;
            p01[0] = (_Float16)s[tt][0]; p01[1] = (_Float16)s[tt][1];
            p23[0] = (_Float16)s[tt][2]; p23[1] = (_Float16)s[tt][3];
            *(half2v*)&P[w][l15][t * 16 + g * 4]     = p01;
            *(half2v*)&P[w][l15][t * 16 + g * 4 + 2] = p23;
        }
        // intra-wave LDS RAW: compiler emits lgkmcnt; no barrier (per-wave region)
        #pragma unroll
        for (int s2i = 0; s2i < 8; ++s2i) {
            half8 bf = *(const half8*)&P[w][l15][s2i * 32 + g * 8];
            half8 a0 = *(const half8*)(vp + hf * 256 + s2i * 32);
            half8 a1 = *(const half8*)(vp + 16 * 512 + hf * 256 + s2i * 32);
            c0 = __builtin_amdgcn_mfma_f32_16x16x32_f16(a0, bf, c0, 0, 0, 0);
            c1 = __builtin_amdgcn_mfma_f32_16x16x32_f16(a1, bf, c1, 0, 0, 0);
        }
    }
    // out: d = {g*4+i, 16+g*4+i}, q = l15 (same lane as rs)
    _Float16* cp = ctx + ((long)b * 512 + q0 + w * 16 + l15) * 256 + h * 32;
    #pragma unroll
    for (int i = 0; i < 4; ++i) {
        cp[g * 4 + i]      = (_Float16)(c0[i] * rs);
        cp[16 + g * 4 + i] = (_Float16)(c1[i] * rs);
    }
}

// ---------------------------------------------------------------- residual + LN
__global__ __launch_bounds__(256) void ln_kernel(
    const float* __restrict__ det, const float* __restrict__ att,
    const float* __restrict__ g, const float* __restrict__ bta,
    _Float16* __restrict__ xn)
{
    int row = blockIdx.x, tid = threadIdx.x;
    long idx = (long)row * 256 + tid;
    float x = det[idx] + att[idx];
    float s1 = x, s2 = x * x;
    #pragma unroll
    for (int off = 32; off; off >>= 1) {
        s1 += __shfl_xor(s1, off, 64);
        s2 += __shfl_xor(s2, off, 64);
    }
    __shared__ float r1[4], r2[4];
    if ((tid & 63) == 0) { r1[tid >> 6] = s1; r2[tid >> 6] = s2; }
    __syncthreads();
    float S1 = r1[0] + r1[1] + r1[2] + r1[3];
    float S2 = r2[0] + r2[1] + r2[2] + r2[3];
    float mean = S1 * (1.f / 256.f);
    float var  = S2 * (1.f / 256.f) - mean * mean;
    float rsv = rsqrtf(var + 1e-5f);
    xn[idx] = (_Float16)((x - mean) * rsv * g[tid] + bta[tid]);
}

// ---------------------------------------------------------------- pairwise MLP
// Swapped orientation: MFMA(A = w1 (.) trk, B = xn).
// Out: row = h' (reg axis), col = n (lane axis). Scaling hits the 2-frag w1
// side (64 pk_mul/tl, was 128). b1 folded into acc init. w2-contraction is
// 8 in-reg fma per n + shfl_xor(16)+shfl_xor(32) (no DPP chains).
__global__ __launch_bounds__(256, 2) void mlp_kernel(
    const _Float16* __restrict__ xn, const _Float16* __restrict__ trk,
    const _Float16* __restrict__ w1, const float* __restrict__ w2,
    const float* __restrict__ b1, const float* __restrict__ b2,
    float* __restrict__ out)
{
    int b  = blockIdx.z;
    int n0 = blockIdx.x * 64;
    int t0 = blockIdx.y * 32;
    int tid = threadIdx.x;
    int l = tid & 63, w = tid >> 6;
    int l15 = l & 15, g = l >> 4;
    int ko = g * 8;

    __shared__ _Float16 ts[32][264];    // tracks tile, padded
    __shared__ float part[4][32][65];   // per-wave fp32 partial logits [w][t][n]

    // stage tracks tile 32x256
    {
        const _Float16* src = trk + ((long)b * 512 + t0) * 256;
        int r = tid >> 3, c0 = (tid & 7) * 8;
        #pragma unroll
        for (int c = 0; c < 256; c += 64)
            *(half8*)(&ts[r][c + c0]) = *(const half8*)(src + r * 256 + c + c0);
    }

    // W1 fragments, A operand: row = h' = w*32 + a*16 + l15, elems d = ks*32+g*8
    half8 wf[2][8];
    {
        const _Float16* w1p = w1 + (w * 32 + l15) * 256 + ko;
        #pragma unroll
        for (int a = 0; a < 2; ++a)
            #pragma unroll
            for (int ks = 0; ks < 8; ++ks)
                wf[a][ks] = *(const half8*)(w1p + a * 16 * 256 + ks * 32);
    }
    // per-lane b1/w2 for h' = w*32 + a*16 + g*4 + i  (reg-axis mapping)
    f32x4 binit[2]; float w2v[2][4];
    #pragma unroll
    for (int a = 0; a < 2; ++a)
        #pragma unroll
        for (int i = 0; i < 4; ++i) {
            int hh = w * 32 + a * 16 + g * 4 + i;
            binit[a][i] = b1[hh];
            w2v[a][i]  = w2[hh];
        }

    // xn fragments, B operand: row = n = n0 + m*16 + l15, elems d = ks*32+g*8
    half8 bx[4][8];
    {
        const _Float16* xb = xn + ((long)b * 512 + n0 + l15) * 256 + ko;
        #pragma unroll
        for (int mm = 0; mm < 4; ++mm)
            #pragma unroll
            for (int ks = 0; ks < 8; ++ks)
                bx[mm][ks] = *(const half8*)(xb + mm * 16 * 256 + ks * 32);
    }

    __syncthreads();

    for (int tl = 0; tl < 32; ++tl) {
        f32x4 acc[2][4];
        #pragma unroll
        for (int a = 0; a < 2; ++a)
            #pragma unroll
            for (int mm = 0; mm < 4; ++mm) acc[a][mm] = binit[a];
        #pragma unroll
        for (int ks = 0; ks < 8; ++ks) {
            half8 tf = *(const half8*)(&ts[tl][ks * 32 + ko]);
            half8 sa0 = wf[0][ks] * tf;   // v_pk_mul_f16 x4
            half8 sa1 = wf[1][ks] * tf;
            #pragma unroll
            for (int mm = 0; mm < 4; ++mm) {
                acc[0][mm] = __builtin_amdgcn_mfma_f32_16x16x32_f16(sa0, bx[mm][ks], acc[0][mm], 0, 0, 0);
                acc[1][mm] = __builtin_amdgcn_mfma_f32_16x16x32_f16(sa1, bx[mm][ks], acc[1][mm], 0, 0, 0);
            }
        }
        // epilogue: relu + w2 dot over 8 reg values, then sum 4 lane-groups
        #pragma unroll
        for (int mm = 0; mm < 4; ++mm) {
            float x = 0.f;
            #pragma unroll
            for (int a = 0; a < 2; ++a)
                #pragma unroll
                for (int i = 0; i < 4; ++i)
                    x = fmaf(fmaxf(acc[a][mm][i], 0.f), w2v[a][i], x);
            x += __shfl_xor(x, 16, 64);
            x += __shfl_xor(x, 32, 64);
            if (g == 0) part[w][tl][mm * 16 + l15] = x;
        }
    }
    __syncthreads();

    // combine 4 wave partials + bias, sigmoid, store
    float b2v = b2[0];
    int t = tid & 31;
    int nbase = tid >> 5;
    float* op = out + ((long)b * 512 + n0) * 512 + t0;
    #pragma unroll
    for (int k = 0; k < 8; ++k) {
        int nn = nbase + k * 8;
        float s = part[0][t][nn] + part[1][t][nn]
                + part[2][t][nn] + part[3][t][nn] + b2v;
        op[(long)nn * 512 + t] = 1.f / (1.f + __expf(-s));
    }
}

// ---------------------------------------------------------------- launch
extern "C" void kernel_launch(void* const* d_in, const int* in_sizes, int n_in,
                              void* d_out, int out_size, void* d_ws, size_t ws_size,
                              hipStream_t stream)
{
    const float* det  = (const float*)d_in[0];
    const float* trk  = (const float*)d_in[1];
    const float* w_q  = (const float*)d_in[2];
    const float* b_q  = (const float*)d_in[3];
    const float* w_k  = (const float*)d_in[4];
    const float* b_k  = (const float*)d_in[5];
    const float* w_v  = (const float*)d_in[6];
    const float* b_v  = (const float*)d_in[7];
    const float* w_o  = (const float*)d_in[8];
    const float* b_o  = (const float*)d_in[9];
    const float* ln_g = (const float*)d_in[10];
    const float* ln_b = (const float*)d_in[11];
    const float* w1   = (const float*)d_in[12];
    const float* b1   = (const float*)d_in[13];
    const float* w2   = (const float*)d_in[14];
    const float* b2   = (const float*)d_in[15];
    float* out = (float*)d_out;

    char* ws = (char*)d_ws;
    const size_t O_DETH = 0;                       // 2048x256 f16   1 MB
    const size_t O_TRKH = O_DETH + (size_t)1048576;
    const size_t O_WQH  = O_TRKH + (size_t)1048576;
    const size_t O_WKH  = O_WQH + 131072;
    const size_t O_WVH  = O_WKH + 131072;
    const size_t O_WOH  = O_WVH + 131072;
    const size_t O_W1H  = O_WOH + 131072;
    const size_t O_QH   = O_W1H + 65536;
    const size_t O_KH   = O_QH + (size_t)1048576;
    const size_t O_VT   = O_KH + (size_t)1048576;  // [bh][d][t] f16 1 MB
    const size_t O_CTXH = O_VT + (size_t)1048576;
    const size_t O_XNH  = O_CTXH + (size_t)1048576;
    const size_t O_ATT  = O_XNH + (size_t)1048576; // fp32 attended 2 MB

    _Float16* det_h  = (_Float16*)(ws + O_DETH);
    _Float16* trk_h  = (_Float16*)(ws + O_TRKH);
    _Float16* wq_h   = (_Float16*)(ws + O_WQH);
    _Float16* wk_h   = (_Float16*)(ws + O_WKH);
    _Float16* wv_h   = (_Float16*)(ws + O_WVH);
    _Float16* wo_h   = (_Float16*)(ws + O_WOH);
    _Float16* w1_h   = (_Float16*)(ws + O_W1H);
    _Float16* Q_h    = (_Float16*)(ws + O_QH);
    _Float16* K_h    = (_Float16*)(ws + O_KH);
    _Float16* vt     = (_Float16*)(ws + O_VT);
    _Float16* ctx_h  = (_Float16*)(ws + O_CTXH);
    _Float16* xn_h   = (_Float16*)(ws + O_XNH);
    float*    att_f  = (float*)(ws + O_ATT);

    CvtJobs cj;
    cj.src[0] = det; cj.dst[0] = det_h; cj.n[0] = 2048 * 256;
    cj.src[1] = trk; cj.dst[1] = trk_h; cj.n[1] = 2048 * 256;
    cj.src[2] = w_q; cj.dst[2] = wq_h;  cj.n[2] = 65536;
    cj.src[3] = w_k; cj.dst[3] = wk_h;  cj.n[3] = 65536;
    cj.src[4] = w_v; cj.dst[4] = wv_h;  cj.n[4] = 65536;
    cj.src[5] = w_o; cj.dst[5] = wo_h;  cj.n[5] = 65536;
    cj.src[6] = w1;  cj.dst[6] = w1_h;  cj.n[6] = 32768;
    cvt_kernel<<<dim3(512, 7), 256, 0, stream>>>(cj);

    // Q = det @ wq^T + bq   (2048x256x256)
    gemm_tn<0><<<dim3(32, 4), 256, 0, stream>>>(det_h, wq_h, Q_h, nullptr, b_q, 1.f,
        2048, 256, 256, 256, 256, 256);
    // K = trk @ wk^T + bk
    gemm_tn<0><<<dim3(32, 4), 256, 0, stream>>>(trk_h, wk_h, K_h, nullptr, b_k, 1.f,
        2048, 256, 256, 256, 256, 256);
    // V = trk @ wv^T + bv, stored transposed as vt[bh*32+d][t]
    gemm_tn<2><<<dim3(32, 4), 256, 0, stream>>>(trk_h, wv_h, vt, nullptr, b_v, 1.f,
        2048, 256, 256, 256, 256, 256);
    // fused scores + softmax + PV
    flash_kernel<<<dim3(8, 32), 256, 0, stream>>>(Q_h, K_h, vt, ctx_h);
    // attended = ctx @ wo^T + bo  (fp32)
    gemm_tn<1><<<dim3(32, 4), 256, 0, stream>>>(ctx_h, wo_h, nullptr, att_f, b_o, 1.f,
        2048, 256, 256, 256, 256, 256);
    // xn = LN(det + attended)  -> fp16
    ln_kernel<<<2048, 256, 0, stream>>>(det, att_f, ln_g, ln_b, xn_h);
    // association MLP + sigmoid
    mlp_kernel<<<dim3(8, 16, 4), 256, 0, stream>>>(xn_h, trk_h, w1_h, w2, b1, b2, out);

    (void)in_sizes; (void)n_in; (void)out_size; (void)ws_size;
}